// Round 7
// baseline (362.492 us; speedup 1.0000x reference)
//
#include <hip/hip_runtime.h>
#include <hip/hip_bf16.h>
#include <math.h>

#define S_LEN 4096
#define DMODEL 2048
#define HEADD 128

typedef __attribute__((ext_vector_type(8))) short short8;
typedef __attribute__((ext_vector_type(4))) float floatx4;

__device__ __forceinline__ short f2bs(float f) {
  __hip_bfloat16 h = __float2bfloat16(f);
  short s; __builtin_memcpy(&s, &h, 2); return s;
}
__device__ __forceinline__ float bs2f(short s) {
  unsigned u = ((unsigned)(unsigned short)s) << 16;
  float f; __builtin_memcpy(&f, &u, 4); return f;
}

// ---- Kernel 1: convert Wq,Wk,Wv (fp32 [128][2048] each) -> wc bf16 [384][2048]
__global__ __launch_bounds__(256) void convw_kernel(const float* __restrict__ wq,
                                                    const float* __restrict__ wk,
                                                    const float* __restrict__ wv,
                                                    short* __restrict__ wc) {
  const int per = 128 * 2048;
  int e = (blockIdx.x * blockDim.x + threadIdx.x) * 4;
  const float* src = (e < per) ? wq : (e < 2 * per) ? wk : wv;
  int off = e & (per - 1);
  float4 v = *(const float4*)(src + off);
  short4 r;
  r.x = f2bs(v.x); r.y = f2bs(v.y); r.z = f2bs(v.z); r.w = f2bs(v.w);
  *(short4*)(wc + e) = r;
}

// ---- Kernel 2: projection GEMM  C[8192][384] = X[8192][2048] @ Wc^T
// grid (256 m-blocks of 32 rows) x (2 n-halves of 192); 256 thr = 4 waves x 48
// cols. 2 blocks/CU = 16 waves/CU (4/SIMD). X+W both prefetched 1 iter ahead.
// W L2 traffic: 512 blocks x 768KB = 384 MB (~11us at L2 BW).
__global__ __launch_bounds__(256, 4) void proj_kernel(const float* __restrict__ x,
                                                      const short* __restrict__ wc,
                                                      short* __restrict__ qb,
                                                      short* __restrict__ kb,
                                                      short* __restrict__ vt) {
  const int w = threadIdx.x >> 6;
  const int lane = threadIdx.x & 63;
  const int lo = lane & 15, g = lane >> 4;
  const int m0 = blockIdx.x * 32;
  const int n0 = blockIdx.y * 192 + w * 48;

  const float* xrow0 = x + (size_t)(m0 + lo) * DMODEL;
  const float* xrow1 = x + (size_t)(m0 + 16 + lo) * DMODEL;
  const short* wrow = wc + (size_t)(n0 + lo) * DMODEL;

  floatx4 acc[3][2];
#pragma unroll
  for (int t = 0; t < 3; ++t)
#pragma unroll
    for (int mm = 0; mm < 2; ++mm) acc[t][mm] = floatx4{0.f, 0.f, 0.f, 0.f};

  float4 a00 = *(const float4*)(xrow0 + g * 8);
  float4 a01 = *(const float4*)(xrow0 + g * 8 + 4);
  float4 a10 = *(const float4*)(xrow1 + g * 8);
  float4 a11 = *(const float4*)(xrow1 + g * 8 + 4);
  short8 wf[3];
#pragma unroll
  for (int t = 0; t < 3; ++t) wf[t] = *(const short8*)(wrow + t * 16 * DMODEL + g * 8);

#pragma unroll 1
  for (int k = 0; k < DMODEL; k += 32) {
    const int kn = (k + 32 < DMODEL) ? k + 32 : 0;
    float4 b00 = *(const float4*)(xrow0 + kn + g * 8);
    float4 b01 = *(const float4*)(xrow0 + kn + g * 8 + 4);
    float4 b10 = *(const float4*)(xrow1 + kn + g * 8);
    float4 b11 = *(const float4*)(xrow1 + kn + g * 8 + 4);
    short8 wn[3];
#pragma unroll
    for (int t = 0; t < 3; ++t) wn[t] = *(const short8*)(wrow + t * 16 * DMODEL + kn + g * 8);

    short8 af0, af1;
    af0[0] = f2bs(a00.x); af0[1] = f2bs(a00.y); af0[2] = f2bs(a00.z); af0[3] = f2bs(a00.w);
    af0[4] = f2bs(a01.x); af0[5] = f2bs(a01.y); af0[6] = f2bs(a01.z); af0[7] = f2bs(a01.w);
    af1[0] = f2bs(a10.x); af1[1] = f2bs(a10.y); af1[2] = f2bs(a10.z); af1[3] = f2bs(a10.w);
    af1[4] = f2bs(a11.x); af1[5] = f2bs(a11.y); af1[6] = f2bs(a11.z); af1[7] = f2bs(a11.w);
#pragma unroll
    for (int t = 0; t < 3; ++t) {
      acc[t][0] = __builtin_amdgcn_mfma_f32_16x16x32_bf16(af0, wf[t], acc[t][0], 0, 0, 0);
      acc[t][1] = __builtin_amdgcn_mfma_f32_16x16x32_bf16(af1, wf[t], acc[t][1], 0, 0, 0);
    }
    a00 = b00; a01 = b01; a10 = b10; a11 = b11;
    wf[0] = wn[0]; wf[1] = wn[1]; wf[2] = wn[2];
  }

#pragma unroll
  for (int t = 0; t < 3; ++t) {
    int n = n0 + t * 16 + lo;
#pragma unroll
    for (int mm = 0; mm < 2; ++mm)
#pragma unroll
      for (int j = 0; j < 4; ++j) {
        int m = m0 + mm * 16 + g * 4 + j;
        if (n < HEADD) {
          qb[(size_t)m * HEADD + n] = f2bs(acc[t][mm][j] * 0.125f);  // fold 1/sqrt(64)
        } else if (n < 2 * HEADD) {
          kb[(size_t)m * HEADD + (n - HEADD)] = f2bs(acc[t][mm][j]);
        } else {
          int h = n - 2 * HEADD;
          int bb = m >> 12, s = m & (S_LEN - 1);
          vt[((size_t)bb * HEADD + h) * S_LEN + s] = f2bs(acc[t][mm][j]);
        }
      }
  }
}

// ---- Kernel 3: dual flash attention, partial-sum producer
// 1024 blocks = (b, qt, kv-half); 256 thr = 4 waves x 512 KV (16 iters of 32).
// No max-subtraction; l via ones-column MFMA; block merge = LDS atomicAdd of
// pure sums; block writes unnormalized bf16 O-partial + fp32 l-partial.
// 4 blocks/CU = 16 waves/CU (4/SIMD). VGPR budget 128 (body ~92).
__global__ __launch_bounds__(256, 4) void attn_kernel(const short* __restrict__ qb,
                                                      const short* __restrict__ kb,
                                                      const short* __restrict__ vt,
                                                      short* __restrict__ po,
                                                      float* __restrict__ pls) {
  const int tid = threadIdx.x;
  const int w = tid >> 6;
  const int lane = tid & 63;
  const int lo = lane & 15, g = lane >> 4;
  // XCD swizzle: per XCD one b and a 64-qt band (K/V slice L2-resident)
  const int id = blockIdx.x;
  const int xcd = id & 7;
  const int b = xcd >> 2;
  const int rest = id >> 3;              // 0..127
  const int qt = (xcd & 3) * 64 + (rest & 63);
  const int half = rest >> 6;            // kv half: 0 or 1

  __shared__ float accb[2 * 16 * 132];   // 16.9 KB, unioned with P staging
  __shared__ float merge_l[2][16];
  short* pl = (short*)accb;              // [4 waves][2 streams][16 rows][36]
  short* plw = pl + w * (2 * 16 * 36);

  const short* qrow = qb + (size_t)(b * S_LEN + qt * 16 + lo) * HEADD;
  const short8 q1f0 = *(const short8*)(qrow + g * 8);
  const short8 q1f1 = *(const short8*)(qrow + 32 + g * 8);
  const short8 q2f0 = *(const short8*)(qrow + 64 + g * 8);
  const short8 q2f1 = *(const short8*)(qrow + 96 + g * 8);

  floatx4 acc1[8], acc2[8];
#pragma unroll
  for (int n = 0; n < 8; ++n) {
    acc1[n] = floatx4{0.f, 0.f, 0.f, 0.f};
    acc2[n] = floatx4{0.f, 0.f, 0.f, 0.f};
  }
  floatx4 lx1 = floatx4{0.f, 0.f, 0.f, 0.f};
  floatx4 lx2 = floatx4{0.f, 0.f, 0.f, 0.f};

  short8 onesb;
  {
    short one = (short)0x3F80;
#pragma unroll
    for (int jj = 0; jj < 8; ++jj) onesb[jj] = (lo == 0) ? one : (short)0;
  }

  const short* kbase = kb + (size_t)b * S_LEN * HEADD;
  const short* vbase = vt + (size_t)b * HEADD * S_LEN;

#pragma unroll 1
  for (int it = 0; it < 16; ++it) {
    const int kv = half * 2048 + w * 512 + it * 32;
    floatx4 S1[2], S2[2];
#pragma unroll
    for (int t = 0; t < 2; ++t) {
      const short* krow = kbase + (size_t)(kv + t * 16 + lo) * HEADD;
      floatx4 z = floatx4{0.f, 0.f, 0.f, 0.f};
      {
        short8 k1f0 = *(const short8*)(krow + g * 8);
        short8 k1f1 = *(const short8*)(krow + 32 + g * 8);
        floatx4 u1 = __builtin_amdgcn_mfma_f32_16x16x32_bf16(q1f0, k1f0, z, 0, 0, 0);
        S1[t] = __builtin_amdgcn_mfma_f32_16x16x32_bf16(q1f1, k1f1, u1, 0, 0, 0);
      }
      {
        short8 k2f0 = *(const short8*)(krow + 64 + g * 8);
        short8 k2f1 = *(const short8*)(krow + 96 + g * 8);
        floatx4 u2 = __builtin_amdgcn_mfma_f32_16x16x32_bf16(q2f0, k2f0, z, 0, 0, 0);
        S2[t] = __builtin_amdgcn_mfma_f32_16x16x32_bf16(q2f1, k2f1, u2, 0, 0, 0);
      }
    }

    // prefetch ALL V for this step (in flight across exp+pack+fence)
    short8 vf[8];
#pragma unroll
    for (int n = 0; n < 8; ++n)
      vf[n] = *(const short8*)(vbase + (size_t)(n * 16 + lo) * S_LEN + kv + g * 8);

    // plain exp (no max subtract), pack P to LDS: P[r=g*4+j][c=t*16+lo]
#pragma unroll
    for (int j = 0; j < 4; ++j) {
      int r = g * 4 + j;
      plw[r * 36 + lo]             = f2bs(__expf(S1[0][j]));
      plw[r * 36 + 16 + lo]        = f2bs(__expf(S1[1][j]));
      plw[(16 + r) * 36 + lo]      = f2bs(__expf(S2[0][j]));
      plw[(16 + r) * 36 + 16 + lo] = f2bs(__expf(S2[1][j]));
    }
    __builtin_amdgcn_sched_barrier(0);
    asm volatile("s_waitcnt lgkmcnt(0)" ::: "memory");
    __builtin_amdgcn_sched_barrier(0);
    short8 pa1 = *(const short8*)(plw + lo * 36 + g * 8);
    short8 pa2 = *(const short8*)(plw + (16 + lo) * 36 + g * 8);

#pragma unroll
    for (int n = 0; n < 8; ++n) {
      acc1[n] = __builtin_amdgcn_mfma_f32_16x16x32_bf16(pa1, vf[n], acc1[n], 0, 0, 0);
      acc2[n] = __builtin_amdgcn_mfma_f32_16x16x32_bf16(pa2, vf[n], acc2[n], 0, 0, 0);
    }
    lx1 = __builtin_amdgcn_mfma_f32_16x16x32_bf16(pa1, onesb, lx1, 0, 0, 0);
    lx2 = __builtin_amdgcn_mfma_f32_16x16x32_bf16(pa2, onesb, lx2, 0, 0, 0);
  }

  // ---- block merge (pure sums) ----
  __syncthreads();
  for (int t = tid; t < 2 * 16 * 132; t += 256) accb[t] = 0.f;
  if (tid < 32) ((float*)merge_l)[tid] = 0.f;
  __syncthreads();
#pragma unroll
  for (int n = 0; n < 8; ++n)
#pragma unroll
    for (int j = 0; j < 4; ++j) {
      atomicAdd(&accb[(0 * 16 + g * 4 + j) * 132 + n * 16 + lo], acc1[n][j]);
      atomicAdd(&accb[(1 * 16 + g * 4 + j) * 132 + n * 16 + lo], acc2[n][j]);
    }
  if (lo == 0) {
#pragma unroll
    for (int j = 0; j < 4; ++j) {
      atomicAdd(&merge_l[0][g * 4 + j], lx1[j]);
      atomicAdd(&merge_l[1][g * 4 + j], lx2[j]);
    }
  }
  __syncthreads();

  // ---- write bf16 O-partial + fp32 l-partial ----
  const size_t pobase = ((((size_t)half * 2 + b) * 256 + qt) * 2) * 16 * 128;
#pragma unroll
  for (int q4 = 0; q4 < 4; ++q4) {
    int e = (q4 * 256 + tid) * 4;          // 0..4095 over [st][16][128]
    int st = e >> 11, r = (e >> 7) & 15, c = e & 127;
    short4 s4;
    s4.x = f2bs(accb[(st * 16 + r) * 132 + c]);
    s4.y = f2bs(accb[(st * 16 + r) * 132 + c + 1]);
    s4.z = f2bs(accb[(st * 16 + r) * 132 + c + 2]);
    s4.w = f2bs(accb[(st * 16 + r) * 132 + c + 3]);
    *(short4*)(po + pobase + e) = s4;
  }
  if (tid < 32) {
    int st = tid >> 4, r = tid & 15;
    pls[((((size_t)half * 2 + b) * 256 + qt) * 32) + st * 16 + r] = merge_l[st][r];
  }
}

// ---- Kernel 4: merge halves + diff combine + RMSNorm -> out
// 1024 blocks x 256 thr; 8 rows/block, 32 lanes/row (4 cols each).
__global__ __launch_bounds__(256) void merge_kernel(const short* __restrict__ po,
                                                    const float* __restrict__ pls,
                                                    const float* __restrict__ lq1,
                                                    const float* __restrict__ lq2,
                                                    const float* __restrict__ lk1,
                                                    const float* __restrict__ lk2,
                                                    const float* __restrict__ rmsw,
                                                    float* __restrict__ out) {
  const int tid = threadIdx.x;
  const int gr = blockIdx.x * 8 + (tid >> 5);
  const int l32 = tid & 31, c0 = l32 * 4;
  const int b = gr >> 12, s = gr & 4095, qt = s >> 4, ri = s & 15;

  float a1s = 0.f, a2s = 0.f;
  for (int i = 0; i < 64; ++i) {
    a1s = fmaf(lq1[i], lk1[i], a1s);
    a2s = fmaf(lq2[i], lk2[i], a2s);
  }
  const float lam = __expf(a1s) - __expf(a2s) + 0.7836057665316245f;

  float o1[4] = {0.f, 0.f, 0.f, 0.f}, o2[4] = {0.f, 0.f, 0.f, 0.f};
  float l1 = 0.f, l2 = 0.f;
#pragma unroll
  for (int half = 0; half < 2; ++half) {
    size_t base = (((size_t)half * 2 + b) * 256 + qt) * 2;
    short4 s1 = *(const short4*)(po + (base + 0) * 2048 + ri * 128 + c0);
    short4 s2 = *(const short4*)(po + (base + 1) * 2048 + ri * 128 + c0);
    o1[0] += bs2f(s1.x); o1[1] += bs2f(s1.y); o1[2] += bs2f(s1.z); o1[3] += bs2f(s1.w);
    o2[0] += bs2f(s2.x); o2[1] += bs2f(s2.y); o2[2] += bs2f(s2.z); o2[3] += bs2f(s2.w);
    l1 += pls[base * 16 + ri];            // base*16 = (half,b,qt)*32
    l2 += pls[base * 16 + 16 + ri];
  }
  const float iL1 = 1.f / l1, iL2 = 1.f / l2;

  float v[4];
  float ssq = 0.f;
#pragma unroll
  for (int k = 0; k < 4; ++k) {
    v[k] = o1[k] * iL1 - lam * (o2[k] * iL2);
    ssq += v[k] * v[k];
  }
#pragma unroll
  for (int d = 1; d < 32; d <<= 1) ssq += __shfl_xor(ssq, d);
  const float rr = rsqrtf(ssq * (1.f / 128.f) + 1.1920928955078125e-07f);

  float4 wv4 = *(const float4*)(rmsw + c0);
  float4 r4;
  r4.x = 0.21639423346837554f * v[0] * rr * wv4.x;
  r4.y = 0.21639423346837554f * v[1] * rr * wv4.y;
  r4.z = 0.21639423346837554f * v[2] * rr * wv4.z;
  r4.w = 0.21639423346837554f * v[3] * rr * wv4.w;
  *(float4*)(out + (size_t)gr * 128 + c0) = r4;
}

extern "C" void kernel_launch(void* const* d_in, const int* in_sizes, int n_in,
                              void* d_out, int out_size, void* d_ws, size_t ws_size,
                              hipStream_t stream) {
  const float* x   = (const float*)d_in[0];
  const float* wq  = (const float*)d_in[1];
  const float* wk  = (const float*)d_in[2];
  const float* wv  = (const float*)d_in[3];
  const float* lq1 = (const float*)d_in[4];
  const float* lq2 = (const float*)d_in[5];
  const float* lk1 = (const float*)d_in[6];
  const float* lk2 = (const float*)d_in[7];
  const float* rw  = (const float*)d_in[8];
  float* out = (float*)d_out;

  char* ws = (char*)d_ws;
  short* qb = (short*)(ws);                    // 2 MB (q pre-scaled 0.125)
  short* kb = (short*)(ws + (2u << 20));       // 2 MB
  short* vt = (short*)(ws + (4u << 20));       // 2 MB (V transposed [b][h][s])
  short* wc = (short*)(ws + (6u << 20));       // 1.5 MB
  short* po = (short*)(ws + (8u << 20));       // 8.4 MB bf16 O-partials
  float* pls = (float*)(ws + (17u << 20));     // 131 KB fp32 l-partials

  convw_kernel<<<768, 256, 0, stream>>>(wq, wk, wv, wc);
  proj_kernel<<<dim3(256, 2), 256, 0, stream>>>(x, wc, qb, kb, vt);
  attn_kernel<<<1024, 256, 0, stream>>>(qb, kb, vt, po, pls);
  merge_kernel<<<1024, 256, 0, stream>>>(po, pls, lq1, lq2, lk1, lk2, rw, out);
}

// Round 8
// 314.829 us; speedup vs baseline: 1.1514x; 1.1514x over previous
//
#include <hip/hip_runtime.h>
#include <hip/hip_bf16.h>
#include <math.h>

#define S_LEN 4096
#define DMODEL 2048
#define HEADD 128

typedef __attribute__((ext_vector_type(8))) short short8;
typedef __attribute__((ext_vector_type(4))) float floatx4;

__device__ __forceinline__ short f2bs(float f) {
  __hip_bfloat16 h = __float2bfloat16(f);
  short s; __builtin_memcpy(&s, &h, 2); return s;
}
__device__ __forceinline__ float bs2f(short s) {
  unsigned u = ((unsigned)(unsigned short)s) << 16;
  float f; __builtin_memcpy(&f, &u, 4); return f;
}

// ---- Kernel 1: convert Wq,Wk,Wv (fp32 [128][2048] each) -> wc bf16 [384][2048]
__global__ __launch_bounds__(256) void convw_kernel(const float* __restrict__ wq,
                                                    const float* __restrict__ wk,
                                                    const float* __restrict__ wv,
                                                    short* __restrict__ wc) {
  const int per = 128 * 2048;
  int e = (blockIdx.x * blockDim.x + threadIdx.x) * 4;
  const float* src = (e < per) ? wq : (e < 2 * per) ? wk : wv;
  int off = e & (per - 1);
  float4 v = *(const float4*)(src + off);
  short4 r;
  r.x = f2bs(v.x); r.y = f2bs(v.y); r.z = f2bs(v.z); r.w = f2bs(v.w);
  *(short4*)(wc + e) = r;
}

// ---- Kernel 2: projection GEMM  C[8192][384] = X[8192][2048] @ Wc^T
// grid (256 m-blocks of 32 rows) x (2 n-halves); 256 thr = 4 waves x 48 cols.
// launch_bounds (256,3): combined VGPR+AGPR ~134 needs cap 170, NOT 128
// (gfx950 unified reg file -- the R7 lesson).
__global__ __launch_bounds__(256, 3) void proj_kernel(const float* __restrict__ x,
                                                      const short* __restrict__ wc,
                                                      short* __restrict__ qb,
                                                      short* __restrict__ kb,
                                                      short* __restrict__ vt) {
  const int w = threadIdx.x >> 6;
  const int lane = threadIdx.x & 63;
  const int lo = lane & 15, g = lane >> 4;
  const int m0 = blockIdx.x * 32;
  const int n0 = blockIdx.y * 192 + w * 48;

  const float* xrow0 = x + (size_t)(m0 + lo) * DMODEL;
  const float* xrow1 = x + (size_t)(m0 + 16 + lo) * DMODEL;
  const short* wrow = wc + (size_t)(n0 + lo) * DMODEL;

  floatx4 acc[3][2];
#pragma unroll
  for (int t = 0; t < 3; ++t)
#pragma unroll
    for (int mm = 0; mm < 2; ++mm) acc[t][mm] = floatx4{0.f, 0.f, 0.f, 0.f};

  float4 a00 = *(const float4*)(xrow0 + g * 8);
  float4 a01 = *(const float4*)(xrow0 + g * 8 + 4);
  float4 a10 = *(const float4*)(xrow1 + g * 8);
  float4 a11 = *(const float4*)(xrow1 + g * 8 + 4);
  short8 wf[3];
#pragma unroll
  for (int t = 0; t < 3; ++t) wf[t] = *(const short8*)(wrow + t * 16 * DMODEL + g * 8);

#pragma unroll 1
  for (int k = 0; k < DMODEL; k += 32) {
    const int kn = (k + 32 < DMODEL) ? k + 32 : 0;
    float4 b00 = *(const float4*)(xrow0 + kn + g * 8);
    float4 b01 = *(const float4*)(xrow0 + kn + g * 8 + 4);
    float4 b10 = *(const float4*)(xrow1 + kn + g * 8);
    float4 b11 = *(const float4*)(xrow1 + kn + g * 8 + 4);
    short8 wn[3];
#pragma unroll
    for (int t = 0; t < 3; ++t) wn[t] = *(const short8*)(wrow + t * 16 * DMODEL + kn + g * 8);

    short8 af0, af1;
    af0[0] = f2bs(a00.x); af0[1] = f2bs(a00.y); af0[2] = f2bs(a00.z); af0[3] = f2bs(a00.w);
    af0[4] = f2bs(a01.x); af0[5] = f2bs(a01.y); af0[6] = f2bs(a01.z); af0[7] = f2bs(a01.w);
    af1[0] = f2bs(a10.x); af1[1] = f2bs(a10.y); af1[2] = f2bs(a10.z); af1[3] = f2bs(a10.w);
    af1[4] = f2bs(a11.x); af1[5] = f2bs(a11.y); af1[6] = f2bs(a11.z); af1[7] = f2bs(a11.w);
#pragma unroll
    for (int t = 0; t < 3; ++t) {
      acc[t][0] = __builtin_amdgcn_mfma_f32_16x16x32_bf16(af0, wf[t], acc[t][0], 0, 0, 0);
      acc[t][1] = __builtin_amdgcn_mfma_f32_16x16x32_bf16(af1, wf[t], acc[t][1], 0, 0, 0);
    }
    a00 = b00; a01 = b01; a10 = b10; a11 = b11;
    wf[0] = wn[0]; wf[1] = wn[1]; wf[2] = wn[2];
  }

#pragma unroll
  for (int t = 0; t < 3; ++t) {
    int n = n0 + t * 16 + lo;
#pragma unroll
    for (int mm = 0; mm < 2; ++mm)
#pragma unroll
      for (int j = 0; j < 4; ++j) {
        int m = m0 + mm * 16 + g * 4 + j;
        if (n < HEADD) {
          qb[(size_t)m * HEADD + n] = f2bs(acc[t][mm][j] * 0.125f);  // fold 1/sqrt(64)
        } else if (n < 2 * HEADD) {
          kb[(size_t)m * HEADD + (n - HEADD)] = f2bs(acc[t][mm][j]);
        } else {
          int h = n - 2 * HEADD;
          int bb = m >> 12, s = m & (S_LEN - 1);
          vt[((size_t)bb * HEADD + h) * S_LEN + s] = f2bs(acc[t][mm][j]);
        }
      }
  }
}

// ---- Kernel 3: dual flash attention, partial-sum producer
// 1024 blocks = (b, qt, kv-half); 256 thr = 4 waves x 512 KV (16 iters of 32).
// launch_bounds (256,3): ~76 VGPR + ~68 AGPR = 144 <= cap 170. (256,4)'s
// 128 cap spills (R7). 3 blocks/CU = 12 waves/CU.
__global__ __launch_bounds__(256, 3) void attn_kernel(const short* __restrict__ qb,
                                                      const short* __restrict__ kb,
                                                      const short* __restrict__ vt,
                                                      short* __restrict__ po,
                                                      float* __restrict__ pls) {
  const int tid = threadIdx.x;
  const int w = tid >> 6;
  const int lane = tid & 63;
  const int lo = lane & 15, g = lane >> 4;
  const int id = blockIdx.x;
  const int xcd = id & 7;
  const int b = xcd >> 2;
  const int rest = id >> 3;              // 0..127
  const int qt = (xcd & 3) * 64 + (rest & 63);
  const int half = rest >> 6;            // kv half: 0 or 1

  __shared__ float accb[2 * 16 * 132];   // 16.9 KB, unioned with P staging
  __shared__ float merge_l[2][16];
  short* pl = (short*)accb;              // [4 waves][2 streams][16 rows][36]
  short* plw = pl + w * (2 * 16 * 36);

  const short* qrow = qb + (size_t)(b * S_LEN + qt * 16 + lo) * HEADD;
  const short8 q1f0 = *(const short8*)(qrow + g * 8);
  const short8 q1f1 = *(const short8*)(qrow + 32 + g * 8);
  const short8 q2f0 = *(const short8*)(qrow + 64 + g * 8);
  const short8 q2f1 = *(const short8*)(qrow + 96 + g * 8);

  floatx4 acc1[8], acc2[8];
#pragma unroll
  for (int n = 0; n < 8; ++n) {
    acc1[n] = floatx4{0.f, 0.f, 0.f, 0.f};
    acc2[n] = floatx4{0.f, 0.f, 0.f, 0.f};
  }
  floatx4 lx1 = floatx4{0.f, 0.f, 0.f, 0.f};
  floatx4 lx2 = floatx4{0.f, 0.f, 0.f, 0.f};

  short8 onesb;
  {
    short one = (short)0x3F80;
#pragma unroll
    for (int jj = 0; jj < 8; ++jj) onesb[jj] = (lo == 0) ? one : (short)0;
  }

  const short* kbase = kb + (size_t)b * S_LEN * HEADD;
  const short* vbase = vt + (size_t)b * HEADD * S_LEN;

#pragma unroll 1
  for (int it = 0; it < 16; ++it) {
    const int kv = half * 2048 + w * 512 + it * 32;
    floatx4 S1[2], S2[2];
#pragma unroll
    for (int t = 0; t < 2; ++t) {
      const short* krow = kbase + (size_t)(kv + t * 16 + lo) * HEADD;
      floatx4 z = floatx4{0.f, 0.f, 0.f, 0.f};
      {
        short8 k1f0 = *(const short8*)(krow + g * 8);
        short8 k1f1 = *(const short8*)(krow + 32 + g * 8);
        floatx4 u1 = __builtin_amdgcn_mfma_f32_16x16x32_bf16(q1f0, k1f0, z, 0, 0, 0);
        S1[t] = __builtin_amdgcn_mfma_f32_16x16x32_bf16(q1f1, k1f1, u1, 0, 0, 0);
      }
      {
        short8 k2f0 = *(const short8*)(krow + 64 + g * 8);
        short8 k2f1 = *(const short8*)(krow + 96 + g * 8);
        floatx4 u2 = __builtin_amdgcn_mfma_f32_16x16x32_bf16(q2f0, k2f0, z, 0, 0, 0);
        S2[t] = __builtin_amdgcn_mfma_f32_16x16x32_bf16(q2f1, k2f1, u2, 0, 0, 0);
      }
    }

    // prefetch first half of V only (reg budget -- R7 lesson)
    short8 vf0[4];
#pragma unroll
    for (int n = 0; n < 4; ++n)
      vf0[n] = *(const short8*)(vbase + (size_t)(n * 16 + lo) * S_LEN + kv + g * 8);

    // plain exp (no max subtract), pack P to LDS: P[r=g*4+j][c=t*16+lo]
#pragma unroll
    for (int j = 0; j < 4; ++j) {
      int r = g * 4 + j;
      plw[r * 36 + lo]             = f2bs(__expf(S1[0][j]));
      plw[r * 36 + 16 + lo]        = f2bs(__expf(S1[1][j]));
      plw[(16 + r) * 36 + lo]      = f2bs(__expf(S2[0][j]));
      plw[(16 + r) * 36 + 16 + lo] = f2bs(__expf(S2[1][j]));
    }
    __builtin_amdgcn_sched_barrier(0);
    asm volatile("s_waitcnt lgkmcnt(0)" ::: "memory");
    __builtin_amdgcn_sched_barrier(0);
    short8 pa1 = *(const short8*)(plw + lo * 36 + g * 8);
    short8 pa2 = *(const short8*)(plw + (16 + lo) * 36 + g * 8);

#pragma unroll
    for (int n = 0; n < 4; ++n) {
      acc1[n] = __builtin_amdgcn_mfma_f32_16x16x32_bf16(pa1, vf0[n], acc1[n], 0, 0, 0);
      acc2[n] = __builtin_amdgcn_mfma_f32_16x16x32_bf16(pa2, vf0[n], acc2[n], 0, 0, 0);
    }
#pragma unroll
    for (int n = 4; n < 8; ++n) {
      short8 vf = *(const short8*)(vbase + (size_t)(n * 16 + lo) * S_LEN + kv + g * 8);
      acc1[n] = __builtin_amdgcn_mfma_f32_16x16x32_bf16(pa1, vf, acc1[n], 0, 0, 0);
      acc2[n] = __builtin_amdgcn_mfma_f32_16x16x32_bf16(pa2, vf, acc2[n], 0, 0, 0);
    }
    lx1 = __builtin_amdgcn_mfma_f32_16x16x32_bf16(pa1, onesb, lx1, 0, 0, 0);
    lx2 = __builtin_amdgcn_mfma_f32_16x16x32_bf16(pa2, onesb, lx2, 0, 0, 0);
  }

  // ---- block merge (pure sums) ----
  __syncthreads();
  for (int t = tid; t < 2 * 16 * 132; t += 256) accb[t] = 0.f;
  if (tid < 32) ((float*)merge_l)[tid] = 0.f;
  __syncthreads();
#pragma unroll
  for (int n = 0; n < 8; ++n)
#pragma unroll
    for (int j = 0; j < 4; ++j) {
      atomicAdd(&accb[(0 * 16 + g * 4 + j) * 132 + n * 16 + lo], acc1[n][j]);
      atomicAdd(&accb[(1 * 16 + g * 4 + j) * 132 + n * 16 + lo], acc2[n][j]);
    }
  if (lo == 0) {
#pragma unroll
    for (int j = 0; j < 4; ++j) {
      atomicAdd(&merge_l[0][g * 4 + j], lx1[j]);
      atomicAdd(&merge_l[1][g * 4 + j], lx2[j]);
    }
  }
  __syncthreads();

  // ---- write bf16 O-partial + fp32 l-partial ----
  const size_t pobase = ((((size_t)half * 2 + b) * 256 + qt) * 2) * 16 * 128;
#pragma unroll
  for (int q4 = 0; q4 < 4; ++q4) {
    int e = (q4 * 256 + tid) * 4;          // 0..4095 over [st][16][128]
    int st = e >> 11, r = (e >> 7) & 15, c = e & 127;
    short4 s4;
    s4.x = f2bs(accb[(st * 16 + r) * 132 + c]);
    s4.y = f2bs(accb[(st * 16 + r) * 132 + c + 1]);
    s4.z = f2bs(accb[(st * 16 + r) * 132 + c + 2]);
    s4.w = f2bs(accb[(st * 16 + r) * 132 + c + 3]);
    *(short4*)(po + pobase + e) = s4;
  }
  if (tid < 32) {
    int st = tid >> 4, r = tid & 15;
    pls[((((size_t)half * 2 + b) * 256 + qt) * 32) + st * 16 + r] = merge_l[st][r];
  }
}

// ---- Kernel 4: merge halves + diff combine + RMSNorm -> out
__global__ __launch_bounds__(256) void merge_kernel(const short* __restrict__ po,
                                                    const float* __restrict__ pls,
                                                    const float* __restrict__ lq1,
                                                    const float* __restrict__ lq2,
                                                    const float* __restrict__ lk1,
                                                    const float* __restrict__ lk2,
                                                    const float* __restrict__ rmsw,
                                                    float* __restrict__ out) {
  const int tid = threadIdx.x;
  const int gr = blockIdx.x * 8 + (tid >> 5);
  const int l32 = tid & 31, c0 = l32 * 4;
  const int b = gr >> 12, s = gr & 4095, qt = s >> 4, ri = s & 15;

  float a1s = 0.f, a2s = 0.f;
  for (int i = 0; i < 64; ++i) {
    a1s = fmaf(lq1[i], lk1[i], a1s);
    a2s = fmaf(lq2[i], lk2[i], a2s);
  }
  const float lam = __expf(a1s) - __expf(a2s) + 0.7836057665316245f;

  float o1[4] = {0.f, 0.f, 0.f, 0.f}, o2[4] = {0.f, 0.f, 0.f, 0.f};
  float l1 = 0.f, l2 = 0.f;
#pragma unroll
  for (int half = 0; half < 2; ++half) {
    size_t base = (((size_t)half * 2 + b) * 256 + qt) * 2;
    short4 s1 = *(const short4*)(po + (base + 0) * 2048 + ri * 128 + c0);
    short4 s2 = *(const short4*)(po + (base + 1) * 2048 + ri * 128 + c0);
    o1[0] += bs2f(s1.x); o1[1] += bs2f(s1.y); o1[2] += bs2f(s1.z); o1[3] += bs2f(s1.w);
    o2[0] += bs2f(s2.x); o2[1] += bs2f(s2.y); o2[2] += bs2f(s2.z); o2[3] += bs2f(s2.w);
    l1 += pls[base * 16 + ri];
    l2 += pls[base * 16 + 16 + ri];
  }
  const float iL1 = 1.f / l1, iL2 = 1.f / l2;

  float v[4];
  float ssq = 0.f;
#pragma unroll
  for (int k = 0; k < 4; ++k) {
    v[k] = o1[k] * iL1 - lam * (o2[k] * iL2);
    ssq += v[k] * v[k];
  }
#pragma unroll
  for (int d = 1; d < 32; d <<= 1) ssq += __shfl_xor(ssq, d);
  const float rr = rsqrtf(ssq * (1.f / 128.f) + 1.1920928955078125e-07f);

  float4 wv4 = *(const float4*)(rmsw + c0);
  float4 r4;
  r4.x = 0.21639423346837554f * v[0] * rr * wv4.x;
  r4.y = 0.21639423346837554f * v[1] * rr * wv4.y;
  r4.z = 0.21639423346837554f * v[2] * rr * wv4.z;
  r4.w = 0.21639423346837554f * v[3] * rr * wv4.w;
  *(float4*)(out + (size_t)gr * 128 + c0) = r4;
}

extern "C" void kernel_launch(void* const* d_in, const int* in_sizes, int n_in,
                              void* d_out, int out_size, void* d_ws, size_t ws_size,
                              hipStream_t stream) {
  const float* x   = (const float*)d_in[0];
  const float* wq  = (const float*)d_in[1];
  const float* wk  = (const float*)d_in[2];
  const float* wv  = (const float*)d_in[3];
  const float* lq1 = (const float*)d_in[4];
  const float* lq2 = (const float*)d_in[5];
  const float* lk1 = (const float*)d_in[6];
  const float* lk2 = (const float*)d_in[7];
  const float* rw  = (const float*)d_in[8];
  float* out = (float*)d_out;

  char* ws = (char*)d_ws;
  short* qb = (short*)(ws);                    // 2 MB (q pre-scaled 0.125)
  short* kb = (short*)(ws + (2u << 20));       // 2 MB
  short* vt = (short*)(ws + (4u << 20));       // 2 MB (V transposed [b][h][s])
  short* wc = (short*)(ws + (6u << 20));       // 1.5 MB
  short* po = (short*)(ws + (8u << 20));       // 8.4 MB bf16 O-partials
  float* pls = (float*)(ws + (17u << 20));     // 131 KB fp32 l-partials

  convw_kernel<<<768, 256, 0, stream>>>(wq, wk, wv, wc);
  proj_kernel<<<dim3(256, 2), 256, 0, stream>>>(x, wc, qb, kb, vt);
  attn_kernel<<<1024, 256, 0, stream>>>(qb, kb, vt, po, pls);
  merge_kernel<<<1024, 256, 0, stream>>>(po, pls, lq1, lq2, lk1, lk2, rw, out);
}

// Round 10
// 191.516 us; speedup vs baseline: 1.8928x; 1.6439x over previous
//
#include <hip/hip_runtime.h>
#include <hip/hip_bf16.h>
#include <math.h>

#define S_LEN 4096
#define DMODEL 2048
#define HEADD 128

typedef __attribute__((ext_vector_type(8))) short short8;
typedef __attribute__((ext_vector_type(4))) float floatx4;

__device__ __forceinline__ short f2bs(float f) {
  __hip_bfloat16 h = __float2bfloat16(f);
  short s; __builtin_memcpy(&s, &h, 2); return s;
}
__device__ __forceinline__ int pkbf(float a, float b) {  // (lo=a, hi=b) bf16 pair
  return (int)(((unsigned)(unsigned short)f2bs(b) << 16) |
               (unsigned)(unsigned short)f2bs(a));
}

// ---- Kernel 1: convert Wq,Wk,Wv (fp32 [128][2048] each) -> wc bf16 [384][2048]
__global__ __launch_bounds__(256) void convw_kernel(const float* __restrict__ wq,
                                                    const float* __restrict__ wk,
                                                    const float* __restrict__ wv,
                                                    short* __restrict__ wc) {
  const int per = 128 * 2048;
  int e = (blockIdx.x * blockDim.x + threadIdx.x) * 4;
  const float* src = (e < per) ? wq : (e < 2 * per) ? wk : wv;
  int off = e & (per - 1);
  float4 v = *(const float4*)(src + off);
  short4 r;
  r.x = f2bs(v.x); r.y = f2bs(v.y); r.z = f2bs(v.z); r.w = f2bs(v.w);
  *(short4*)(wc + e) = r;
}

// ---- Kernel 2: projection GEMM (unchanged from R8 to isolate attn change)
__global__ __launch_bounds__(256, 3) void proj_kernel(const float* __restrict__ x,
                                                      const short* __restrict__ wc,
                                                      short* __restrict__ qm,
                                                      short* __restrict__ kb,
                                                      short* __restrict__ vt) {
  const int w = threadIdx.x >> 6;
  const int lane = threadIdx.x & 63;
  const int lo = lane & 15, g = lane >> 4;
  const int m0 = blockIdx.x * 32;
  const int n0 = blockIdx.y * 192 + w * 48;

  const float* xrow0 = x + (size_t)(m0 + lo) * DMODEL;
  const float* xrow1 = x + (size_t)(m0 + 16 + lo) * DMODEL;
  const short* wrow = wc + (size_t)(n0 + lo) * DMODEL;

  floatx4 acc[3][2];
#pragma unroll
  for (int t = 0; t < 3; ++t)
#pragma unroll
    for (int mm = 0; mm < 2; ++mm) acc[t][mm] = floatx4{0.f, 0.f, 0.f, 0.f};

  float4 a00 = *(const float4*)(xrow0 + g * 8);
  float4 a01 = *(const float4*)(xrow0 + g * 8 + 4);
  float4 a10 = *(const float4*)(xrow1 + g * 8);
  float4 a11 = *(const float4*)(xrow1 + g * 8 + 4);
  short8 wf[3];
#pragma unroll
  for (int t = 0; t < 3; ++t) wf[t] = *(const short8*)(wrow + t * 16 * DMODEL + g * 8);

#pragma unroll 1
  for (int k = 0; k < DMODEL; k += 32) {
    const int kn = (k + 32 < DMODEL) ? k + 32 : 0;
    float4 b00 = *(const float4*)(xrow0 + kn + g * 8);
    float4 b01 = *(const float4*)(xrow0 + kn + g * 8 + 4);
    float4 b10 = *(const float4*)(xrow1 + kn + g * 8);
    float4 b11 = *(const float4*)(xrow1 + kn + g * 8 + 4);
    short8 wn[3];
#pragma unroll
    for (int t = 0; t < 3; ++t) wn[t] = *(const short8*)(wrow + t * 16 * DMODEL + kn + g * 8);

    short8 af0, af1;
    af0[0] = f2bs(a00.x); af0[1] = f2bs(a00.y); af0[2] = f2bs(a00.z); af0[3] = f2bs(a00.w);
    af0[4] = f2bs(a01.x); af0[5] = f2bs(a01.y); af0[6] = f2bs(a01.z); af0[7] = f2bs(a01.w);
    af1[0] = f2bs(a10.x); af1[1] = f2bs(a10.y); af1[2] = f2bs(a10.z); af1[3] = f2bs(a10.w);
    af1[4] = f2bs(a11.x); af1[5] = f2bs(a11.y); af1[6] = f2bs(a11.z); af1[7] = f2bs(a11.w);
#pragma unroll
    for (int t = 0; t < 3; ++t) {
      acc[t][0] = __builtin_amdgcn_mfma_f32_16x16x32_bf16(af0, wf[t], acc[t][0], 0, 0, 0);
      acc[t][1] = __builtin_amdgcn_mfma_f32_16x16x32_bf16(af1, wf[t], acc[t][1], 0, 0, 0);
    }
    a00 = b00; a01 = b01; a10 = b10; a11 = b11;
    wf[0] = wn[0]; wf[1] = wn[1]; wf[2] = wn[2];
  }

#pragma unroll
  for (int t = 0; t < 3; ++t) {
    int n = n0 + t * 16 + lo;
#pragma unroll
    for (int mm = 0; mm < 2; ++mm)
#pragma unroll
      for (int j = 0; j < 4; ++j) {
        int m = m0 + mm * 16 + g * 4 + j;
        if (n < HEADD) {
          qm[(size_t)m * HEADD + n] = f2bs(acc[t][mm][j] * 0.125f);  // fold 1/sqrt(64)
        } else if (n < 2 * HEADD) {
          kb[(size_t)m * HEADD + (n - HEADD)] = f2bs(acc[t][mm][j]);
        } else {
          int h = n - 2 * HEADD;
          int bb = m >> 12, s = m & (S_LEN - 1);
          vt[((size_t)bb * HEADD + h) * S_LEN + s] = f2bs(acc[t][mm][j]);
        }
      }
  }
}

// ---- Kernel 3: LDS-staged flash attention -> fp32 atomic partial accumulators
// 512 blocks = 128 qblk (64 rows, GLOBAL over b=qblk>>6) x 4 kv-quarters.
// 512 thr = 8 waves = (q-sub 0..3) x (stream 0|1). Per 32-kv step: K/V tile
// (16KB) reg-staged into LDS (dbuf, 1 barrier/step), shared by all 8 waves.
// Swapped QK^T -> in-register P transpose via shfl. No max-subtract; l via
// VALU reduce. Exactly 2 blocks/CU, 16 waves/CU.
__global__ __launch_bounds__(512, 4) void attn_kernel(const short* __restrict__ qm,
                                                      const short* __restrict__ kb,
                                                      const short* __restrict__ vt,
                                                      float* __restrict__ ao,
                                                      float* __restrict__ al) {
  const int tid = threadIdx.x;
  const int w = tid >> 6;
  const int lane = tid & 63;
  const int lo = lane & 15, g = lane >> 4;
  const int qs = w >> 1;            // q-subtile 0..3
  const int s = w & 1;              // attn stream
  const int id = blockIdx.x;
  const int qblk = id >> 2;         // 0..127 global (b folded: b = qblk>>6)
  const int ksp = id & 3;           // kv quarter (1024 kv, 32 steps)
  const int b = qblk >> 6;
  const int kv_base = ksp * 1024;

  __shared__ short kt[2][32][136];  // K tile (pad 8)
  __shared__ short vl[2][128][40];  // V^T tile (pad 8)

  const int kr = tid >> 4, kc = tid & 15;   // K stage: row 0..31, 16B chunk
  const int vh = tid >> 2, vc = tid & 3;    // V stage: head-row 0..127, chunk
  const short* kS = kb + (size_t)b * S_LEN * HEADD;
  const short* vS = vt + (size_t)b * HEADD * S_LEN;

  const int rowq = qblk * 64 + qs * 16;     // global q row 0..8191
  const short* qrow = qm + (size_t)(rowq + lo) * HEADD + s * 64;
  const short8 qf0 = *(const short8*)(qrow + g * 8);
  const short8 qf1 = *(const short8*)(qrow + 32 + g * 8);

  floatx4 acc[8];
#pragma unroll
  for (int n = 0; n < 8; ++n) acc[n] = floatx4{0.f, 0.f, 0.f, 0.f};
  float lx = 0.f;

  const int gA = (g & 1) * 2;
  const int idx0 = lo + 16 * gA, idx1 = idx0 + 16;
  const bool hi = (g >= 2);

  // prologue: stage step 0
  {
    int4 k0 = *(const int4*)(kS + (size_t)(kv_base + kr) * HEADD + kc * 8);
    int4 v0 = *(const int4*)(vS + (size_t)vh * S_LEN + kv_base + vc * 8);
    *(int4*)(&kt[0][kr][kc * 8]) = k0;
    *(int4*)(&vl[0][vh][vc * 8]) = v0;
  }
  __syncthreads();

  int cur = 0;
#pragma unroll 1
  for (int it = 0; it < 32; ++it) {
    int4 knx, vnx;
    if (it + 1 < 32) {                      // issue next-step loads early (T14)
      const int kvn = kv_base + (it + 1) * 32;
      knx = *(const int4*)(kS + (size_t)(kvn + kr) * HEADD + kc * 8);
      vnx = *(const int4*)(vS + (size_t)vh * S_LEN + kvn + vc * 8);
    }

    // QK^T swapped: A = K rows (kv), B = Q cols (q-rows) -> P lane-local
    floatx4 z = floatx4{0.f, 0.f, 0.f, 0.f};
    const short* kp0 = &kt[cur][lo][s * 64 + g * 8];
    short8 a00 = *(const short8*)(kp0);
    short8 a01 = *(const short8*)(kp0 + 32);
    floatx4 u0 = __builtin_amdgcn_mfma_f32_16x16x32_bf16(a00, qf0, z, 0, 0, 0);
    floatx4 T0 = __builtin_amdgcn_mfma_f32_16x16x32_bf16(a01, qf1, u0, 0, 0, 0);
    const short* kp1 = &kt[cur][16 + lo][s * 64 + g * 8];
    short8 a10 = *(const short8*)(kp1);
    short8 a11 = *(const short8*)(kp1 + 32);
    floatx4 u1 = __builtin_amdgcn_mfma_f32_16x16x32_bf16(a10, qf0, z, 0, 0, 0);
    floatx4 T1 = __builtin_amdgcn_mfma_f32_16x16x32_bf16(a11, qf1, u1, 0, 0, 0);

    // plain exp: lane holds P[q=lo][kv = t*16 + g*4 + r]
    float p0 = __expf(T0[0]), p1 = __expf(T0[1]), p2 = __expf(T0[2]), p3 = __expf(T0[3]);
    float p4 = __expf(T1[0]), p5 = __expf(T1[1]), p6 = __expf(T1[2]), p7 = __expf(T1[3]);

    // l: row-sum over 32 kv (in-lane 8 + reduce across g groups)
    float lp = ((p0 + p1) + (p2 + p3)) + ((p4 + p5) + (p6 + p7));
    lp += __shfl_xor(lp, 16);
    lp += __shfl_xor(lp, 32);
    lx += lp;

    // in-register transpose D-layout -> A-layout (bf16 pairs + shfl gather)
    int c00 = pkbf(p0, p1), c01 = pkbf(p2, p3);
    int c10 = pkbf(p4, p5), c11 = pkbf(p6, p7);
    int t0a = __shfl(c00, idx0), t0b = __shfl(c01, idx0);
    int t0c = __shfl(c00, idx1), t0d = __shfl(c01, idx1);
    int t1a = __shfl(c10, idx0), t1b = __shfl(c11, idx0);
    int t1c = __shfl(c10, idx1), t1d = __shfl(c11, idx1);
    int w0 = hi ? t1a : t0a, w1 = hi ? t1b : t0b;
    int w2 = hi ? t1c : t0c, w3 = hi ? t1d : t0d;
    short8 pa;
    { int4 tmp = {w0, w1, w2, w3}; __builtin_memcpy(&pa, &tmp, 16); }

    // PV: B-frags from V^T LDS tile
#pragma unroll
    for (int n = 0; n < 8; ++n) {
      short8 vf = *(const short8*)(&vl[cur][n * 16 + lo][g * 8]);
      acc[n] = __builtin_amdgcn_mfma_f32_16x16x32_bf16(pa, vf, acc[n], 0, 0, 0);
    }

    if (it + 1 < 32) {                      // write next tile into other buffer
      *(int4*)(&kt[cur ^ 1][kr][kc * 8]) = knx;
      *(int4*)(&vl[cur ^ 1][vh][vc * 8]) = vnx;
    }
    __syncthreads();
    cur ^= 1;
  }

  // ---- fp32 atomic merge into global accumulators ----
  float* aw = ao + ((size_t)s * 8192 + rowq) * 128;
#pragma unroll
  for (int n = 0; n < 8; ++n)
#pragma unroll
    for (int j = 0; j < 4; ++j)
      atomicAdd(&aw[(size_t)(g * 4 + j) * 128 + n * 16 + lo], acc[n][j]);
  if (g == 0)
    atomicAdd(&al[(size_t)s * 8192 + rowq + lo], lx);
}

// ---- Kernel 4: normalize + diff combine + RMSNorm -> out
__global__ __launch_bounds__(256) void merge_kernel(const float* __restrict__ ao,
                                                    const float* __restrict__ al,
                                                    const float* __restrict__ lq1,
                                                    const float* __restrict__ lq2,
                                                    const float* __restrict__ lk1,
                                                    const float* __restrict__ lk2,
                                                    const float* __restrict__ rmsw,
                                                    float* __restrict__ out) {
  const int tid = threadIdx.x;
  const int gr = blockIdx.x * 8 + (tid >> 5);
  const int c0 = (tid & 31) * 4;

  float a1s = 0.f, a2s = 0.f;
  for (int i = 0; i < 64; ++i) {
    a1s = fmaf(lq1[i], lk1[i], a1s);
    a2s = fmaf(lq2[i], lk2[i], a2s);
  }
  const float lam = __expf(a1s) - __expf(a2s) + 0.7836057665316245f;

  float4 o1 = *(const float4*)(ao + ((size_t)0 * 8192 + gr) * 128 + c0);
  float4 o2 = *(const float4*)(ao + ((size_t)1 * 8192 + gr) * 128 + c0);
  const float iL1 = 1.f / al[gr];
  const float iL2 = 1.f / al[8192 + gr];

  float v[4];
  v[0] = o1.x * iL1 - lam * (o2.x * iL2);
  v[1] = o1.y * iL1 - lam * (o2.y * iL2);
  v[2] = o1.z * iL1 - lam * (o2.z * iL2);
  v[3] = o1.w * iL1 - lam * (o2.w * iL2);
  float ssq = v[0] * v[0] + v[1] * v[1] + v[2] * v[2] + v[3] * v[3];
#pragma unroll
  for (int d = 1; d < 32; d <<= 1) ssq += __shfl_xor(ssq, d);
  const float rr = rsqrtf(ssq * (1.f / 128.f) + 1.1920928955078125e-07f);

  float4 wv4 = *(const float4*)(rmsw + c0);
  float4 r4;
  r4.x = 0.21639423346837554f * v[0] * rr * wv4.x;
  r4.y = 0.21639423346837554f * v[1] * rr * wv4.y;
  r4.z = 0.21639423346837554f * v[2] * rr * wv4.z;
  r4.w = 0.21639423346837554f * v[3] * rr * wv4.w;
  *(float4*)(out + (size_t)gr * 128 + c0) = r4;
}

extern "C" void kernel_launch(void* const* d_in, const int* in_sizes, int n_in,
                              void* d_out, int out_size, void* d_ws, size_t ws_size,
                              hipStream_t stream) {
  const float* x   = (const float*)d_in[0];
  const float* wq  = (const float*)d_in[1];
  const float* wk  = (const float*)d_in[2];
  const float* wv  = (const float*)d_in[3];
  const float* lq1 = (const float*)d_in[4];
  const float* lq2 = (const float*)d_in[5];
  const float* lk1 = (const float*)d_in[6];
  const float* lk2 = (const float*)d_in[7];
  const float* rw  = (const float*)d_in[8];
  float* out = (float*)d_out;

  char* ws = (char*)d_ws;
  short* qm = (short*)(ws);                    // 2 MB (q pre-scaled 0.125)
  short* kb = (short*)(ws + (2u << 20));       // 2 MB
  short* vt = (short*)(ws + (4u << 20));       // 2 MB (V transposed [b][h][s])
  short* wc = (short*)(ws + (6u << 20));       // 1.5 MB
  float* ao = (float*)(ws + (8u << 20));       // 8 MB fp32 O accumulators [2][8192][128]
  float* al = (float*)(ws + (8u << 20) + 8388608u);  // 64 KB fp32 l accumulators [2][8192]

  // zero the atomic accumulators (graph-capturable async memset)
  hipMemsetAsync(ws + (8u << 20), 0, 8388608u + 65536u, stream);

  convw_kernel<<<768, 256, 0, stream>>>(wq, wk, wv, wc);
  proj_kernel<<<dim3(256, 2), 256, 0, stream>>>(x, wc, qm, kb, vt);
  attn_kernel<<<512, 512, 0, stream>>>(qm, kb, vt, ao, al);
  merge_kernel<<<1024, 256, 0, stream>>>(ao, al, lq1, lq2, lk1, lk2, rw, out);
}